// Round 14
// baseline (370.770 us; speedup 1.0000x reference)
//
#include <hip/hip_runtime.h>
#include <stdint.h>

// AWQ 4-bit dequant GEMM: out[M,N] = x[M,K] @ W[N,K]^T + bias
// Path 2 (ws >= X+W): prepass x->fp16 (row-major, pair-perm + period-4 swizzle,
//   for glds->LDS) and W->fp16 FRAG-MAJOR (1 KB per 16row x 32k frag-tile, pair-
//   perm baked) into d_ws. GEMM: BM=256 BN=128 BK=32, 512 thr (8 waves 4Mx2N of
//   64x64). A: glds->LDS triple-buffer (48 KB -> 2 blocks/CU). B: DIRECT
//   global->reg, coalesced 1KB loads, depth-1 prefetch -- zero B LDS traffic.
//   Tile end: counted s_waitcnt vmcnt(6) + s_barrier (loads fly across barriers).
// Rationale: R13 showed the LDS pipe (reads+glds writes ~1900cyc/tile-pair) was
// 1.9x the MFMA pipe (1030) -> MfmaUtil capped ~38%. Moving B out of LDS
// halves LDS traffic to ~1020 ~= MFMA -> pipes can fully overlap.

typedef _Float16 f16x2 __attribute__((ext_vector_type(2)));
typedef _Float16 f16x8 __attribute__((ext_vector_type(8)));
typedef float f32x4 __attribute__((ext_vector_type(4)));
typedef unsigned int u32x4 __attribute__((ext_vector_type(4)));

// ---------- prepass: x -> fp16 row-major, pair-perm, period-4 swizzle --------
__global__ void convert_x2_kernel(const float* __restrict__ x,
                                  unsigned short* __restrict__ xh,
                                  int M, int K) {
    int g = blockIdx.x * blockDim.x + threadIdx.x;
    int kc = K >> 3;
    if (g >= M * kc) return;
    int r  = g / kc;
    int cc = g - r * kc;
    int csrc = (cc & ~3) | ((cc & 3) ^ ((r >> 1) & 3));
    const float* p = x + (size_t)r * K + (csrc << 3);
    float4 f0 = *reinterpret_cast<const float4*>(p);
    float4 f1 = *reinterpret_cast<const float4*>(p + 4);
    u32x4 o;
    o.x = __builtin_bit_cast(uint32_t, __builtin_amdgcn_cvt_pkrtz(f0.x, f1.x));
    o.y = __builtin_bit_cast(uint32_t, __builtin_amdgcn_cvt_pkrtz(f0.y, f1.y));
    o.z = __builtin_bit_cast(uint32_t, __builtin_amdgcn_cvt_pkrtz(f0.z, f1.z));
    o.w = __builtin_bit_cast(uint32_t, __builtin_amdgcn_cvt_pkrtz(f0.w, f1.w));
    u32x4* dst = reinterpret_cast<u32x4*>(xh + (size_t)r * K + (cc << 3));
    __builtin_nontemporal_store(o, dst);
}

// ---------- prepass: W int4 -> fp16 FRAG-MAJOR dequant ----------------------
// dest chunk d (16B): l=d&63, kt=(d>>6)%(K/32), gg=(d>>6)/(K/32)
// source: row o=gg*16+(l&15), dword qw[o][kt*4 + (l>>4)]
// chunk holds k = kt*32 + (l>>4)*8 + {0,4,1,5,2,6,3,7} (pair-permuted)
__global__ void convert_w3_kernel(const int* __restrict__ qw,
                                  const int* __restrict__ qz,
                                  const float* __restrict__ sc,
                                  unsigned short* __restrict__ whf,
                                  int Nrows, int K) {
    int d = blockIdx.x * blockDim.x + threadIdx.x;
    int kt32 = K >> 5;
    int total = Nrows * (K >> 3);
    if (d >= total) return;
    int l   = d & 63;
    int rest = d >> 6;
    int kt  = rest % kt32;
    int gg  = rest / kt32;
    int o   = gg * 16 + (l & 15);
    int c   = l >> 4;
    int ngrp = K >> 7, nzw = ngrp >> 3;
    int grp = kt >> 2;
    float s = sc[(size_t)o * ngrp + grp];
    uint32_t z = ((uint32_t)qz[(size_t)o * nzw + (grp >> 3)] >> ((grp & 7) << 2)) & 0xF;
    uint32_t u = (uint32_t)qw[(size_t)o * (K >> 3) + kt * 4 + c];
    _Float16 hs = (_Float16)s;
    _Float16 hz = (_Float16)(1024.0f + (float)z);   // integer <=1039: exact fp16
    f16x2 s2 = {hs, hs}, z2 = {hz, hz};
    const uint32_t MK = 0x000F000Fu, MG = 0x64006400u;
    uint32_t p0 = (u & MK) | MG;
    uint32_t p1 = ((u >> 4) & MK) | MG;
    uint32_t p2 = ((u >> 8) & MK) | MG;
    uint32_t p3 = ((u >> 12) & MK) | MG;
    u32x4 ov;
    ov.x = __builtin_bit_cast(uint32_t, (__builtin_bit_cast(f16x2, p0) - z2) * s2);
    ov.y = __builtin_bit_cast(uint32_t, (__builtin_bit_cast(f16x2, p1) - z2) * s2);
    ov.z = __builtin_bit_cast(uint32_t, (__builtin_bit_cast(f16x2, p2) - z2) * s2);
    ov.w = __builtin_bit_cast(uint32_t, (__builtin_bit_cast(f16x2, p3) - z2) * s2);
    __builtin_nontemporal_store(ov, reinterpret_cast<u32x4*>(whf + (size_t)d * 8));
}

// ---------- path 2 GEMM: A via LDS, B direct-to-reg -------------------------
__global__ __launch_bounds__(512, 4) void awq_gemm2_kernel(
    const unsigned short* __restrict__ xh,
    const unsigned short* __restrict__ whf,
    const float* __restrict__ bias,
    float* __restrict__ out,
    int M, int N, int K)
{
    extern __shared__ __align__(16) unsigned short lds[];
    const int ATSZ = 256 * 32;                // 16 KB per A buffer
    unsigned short* As = lds;                 // [3][ATSZ]

    const int tid  = threadIdx.x;
    const int lane = tid & 63;
    const int wave = tid >> 6;
    const int wr   = wave & 3;                // 64-row quarter of 256
    const int wc   = wave >> 2;               // 64-col half of 128
    const int lrow = lane & 15;
    const int cswz = (((lane >> 4) ^ ((lrow >> 1) & 3)) << 3);

    const int cpx = gridDim.x >> 3;
    const int bid = (blockIdx.x & 7) * cpx + (blockIdx.x >> 3);
    const int ntn = N / 128;                  // 32
    const int m0 = (bid / ntn) * 256;
    const int n0 = (bid % ntn) * 128;
    const int NT = K / 32;
    const int kt32 = K >> 5;

    f32x4 acc[4][4];
    #pragma unroll
    for (int m = 0; m < 4; ++m)
        #pragma unroll
        for (int n = 0; n < 4; ++n)
            #pragma unroll
            for (int e = 0; e < 4; ++e) acc[m][n][e] = 0.f;

    // B frag-tile bases: group g = n0/16 + wc*4 + n
    const unsigned short* bbase[4];
    #pragma unroll
    for (int n = 0; n < 4; ++n) {
        int g = (n0 >> 4) + wc * 4 + n;
        bbase[n] = whf + ((size_t)g * kt32) * 512 + lane * 8;
    }

    auto GLDSA = [&](int kt, unsigned short* dst) {
        #pragma unroll
        for (int i = 0; i < 2; ++i) {
            int row = wave * 32 + i * 16 + (lane >> 2);
            const unsigned short* g = xh + (size_t)(m0 + row) * K + kt + ((lane & 3) << 3);
            unsigned short* d = dst + row * 32 + ((lane & 3) << 3);
            __builtin_amdgcn_global_load_lds(
                (const __attribute__((address_space(1))) unsigned int*)g,
                (__attribute__((address_space(3))) unsigned int*)d, 16, 0, 0);
        }
    };

    uint4 bq[4];
    auto LOADB = [&](int kt) {
        #pragma unroll
        for (int n = 0; n < 4; ++n)
            bq[n] = *reinterpret_cast<const uint4*>(bbase[n] + (size_t)kt * 512);
    };

    // ---- prologue: B(0) -> regs; A tiles 0,1 -> LDS bufs 0,1
    LOADB(0);
    GLDSA(0, As);
    if (NT > 1) GLDSA(32, As + ATSZ);
    asm volatile("s_waitcnt vmcnt(0)" ::: "memory");
    __syncthreads();

    for (int t = 0; t < NT; ++t) {
        const int buf = t % 3;
        const unsigned short* Ab = As + buf * ATSZ;
        const bool deep = (t + 2 < NT);

        // A frags from LDS; B frags already in regs
        f16x8 af[4], bf[4];
        #pragma unroll
        for (int n = 0; n < 4; ++n) bf[n] = __builtin_bit_cast(f16x8, bq[n]);
        #pragma unroll
        for (int m = 0; m < 4; ++m) {
            int row = wr * 64 + m * 16 + lrow;
            af[m] = __builtin_bit_cast(f16x8,
                    *reinterpret_cast<const uint4*>(&Ab[row * 32 + cswz]));
        }
        #pragma unroll
        for (int m = 0; m < 4; ++m)
            #pragma unroll
            for (int n = 0; n < 4; ++n)
                acc[m][n] = __builtin_amdgcn_mfma_f32_16x16x32_f16(
                    af[m], bf[n], acc[m][n], 0, 0, 0);

        // reload B regs for t+1 (WAR after MFMA issue; ~1 tile to land)
        if (t + 1 < NT) LOADB(t + 1);
        // stage A for t+2
        if (deep) GLDSA((t + 2) * 32, As + ((t + 2) % 3) * ATSZ);

        // counted waits: leave only this tile's issued loads in flight;
        // everything older (incl. t+1's A-glds) retired before the barrier.
        if (deep) {
            asm volatile("s_waitcnt vmcnt(6)" ::: "memory");   // 4 B + 2 A-glds
            __builtin_amdgcn_s_barrier();
        } else if (t + 1 < NT) {
            asm volatile("s_waitcnt vmcnt(4)" ::: "memory");   // 4 B loads only
            __builtin_amdgcn_s_barrier();
        }
        // last tile: no barrier needed
    }

    // epilogue: C frag col=lane&15, row=(lane>>4)*4+e
    const int r4 = (lane >> 4) << 2;
    #pragma unroll
    for (int n = 0; n < 4; ++n) {
        int col = n0 + wc * 64 + n * 16 + lrow;
        float bv = bias[col];
        #pragma unroll
        for (int m = 0; m < 4; ++m) {
            size_t rbase = (size_t)(m0 + wr * 64 + m * 16 + r4) * N + col;
            #pragma unroll
            for (int e = 0; e < 4; ++e)
                __builtin_nontemporal_store(acc[m][n][e] + bv, &out[rbase + (size_t)e * N]);
        }
    }
}

// ================= fallback (ws too small): R10-style reg-staged ============
#define BM 256
#define BN 256
#define BK 64

__global__ __launch_bounds__(512, 2) void awq_gemm0_kernel(
    const float* __restrict__ x,
    const int*   __restrict__ qw,
    const int*   __restrict__ qz,
    const float* __restrict__ sc,
    const float* __restrict__ bias,
    float*       __restrict__ out,
    int M, int N, int K)
{
    extern __shared__ __align__(16) unsigned short lds[];
    const int ASZ  = BM * BK;
    const int BPSZ = BN * (BK / 8);
    unsigned short* As = lds;
    uint32_t* Bp = reinterpret_cast<uint32_t*>(lds + 2 * ASZ);

    const int tid  = threadIdx.x;
    const int lane = tid & 63;
    const int wave = tid >> 6;
    const int wr   = wave >> 2;
    const int wc   = wave & 3;
    const int lrow = lane & 15;
    const int lko  = (lane >> 4) << 3;
    const int swr  = (lrow & 7) << 3;

    const int cpx = gridDim.x >> 3;
    const int bid = (blockIdx.x & 7) * cpx + (blockIdx.x >> 3);
    const int ntn = N / BN;
    const int m0 = (bid / ntn) * BM;
    const int n0 = (bid % ntn) * BN;

    const int ngrp = K >> 7;
    const int nzw  = ngrp >> 3;
    const int kw   = K >> 3;
    const int NT   = K / BK;

    const int r_s = tid >> 1;
    const int kh  = tid & 1;
    const int sws = (r_s & 7) << 3;

    f32x4 acc[8][4];
    #pragma unroll
    for (int m = 0; m < 8; ++m)
        #pragma unroll
        for (int n = 0; n < 4; ++n)
            #pragma unroll
            for (int e = 0; e < 4; ++e) acc[m][n][e] = 0.f;

    float    sc_pf[4];
    uint32_t zq_pf[4];
    f16x2    ss[4], zz[4];
    auto PFG = [&](int grp) {
        #pragma unroll
        for (int n = 0; n < 4; ++n) {
            int og = n0 + wc * 64 + n * 16 + lrow;
            sc_pf[n] = sc[(size_t)og * ngrp + grp];
            zq_pf[n] = (uint32_t)qz[(size_t)og * nzw + (grp >> 3)];
        }
    };
    auto SETG = [&](int grp) {
        #pragma unroll
        for (int n = 0; n < 4; ++n) {
            _Float16 s = (_Float16)sc_pf[n];
            uint32_t z = (zq_pf[n] >> ((grp & 7) << 2)) & 0xF;
            _Float16 Z = (_Float16)(float)(1024u + z);
            ss[n][0] = s; ss[n][1] = s;
            zz[n][0] = Z; zz[n][1] = Z;
        }
    };

    float4 a32[8];

    auto GLDSB = [&](int kt, uint32_t* Bw) {
        int row = tid >> 1;
        const int* g = qw + (size_t)(n0 + row) * kw + (kt >> 3) + (tid & 1) * 4;
        uint32_t* d = Bw + row * 8 + (tid & 1) * 4;
        __builtin_amdgcn_global_load_lds(
            (const __attribute__((address_space(1))) unsigned int*)g,
            (__attribute__((address_space(3))) unsigned int*)d, 16, 0, 0);
    };
    auto LOADA = [&](int kt) {
        const float* p = x + (size_t)(m0 + r_s) * K + kt + kh * 32;
        #pragma unroll
        for (int i = 0; i < 8; ++i)
            a32[i] = *reinterpret_cast<const float4*>(p + 4 * i);
    };
    auto WA = [&](unsigned short* dst, int c) {
        uint4 o;
        o.x = __builtin_bit_cast(uint32_t, __builtin_amdgcn_cvt_pkrtz(a32[2*c].x, a32[2*c+1].x));
        o.y = __builtin_bit_cast(uint32_t, __builtin_amdgcn_cvt_pkrtz(a32[2*c].y, a32[2*c+1].y));
        o.z = __builtin_bit_cast(uint32_t, __builtin_amdgcn_cvt_pkrtz(a32[2*c].z, a32[2*c+1].z));
        o.w = __builtin_bit_cast(uint32_t, __builtin_amdgcn_cvt_pkrtz(a32[2*c].w, a32[2*c+1].w));
        int kcol = kh * 32 + 8 * c;
        *reinterpret_cast<uint4*>(&dst[r_s * BK + (kcol ^ sws)]) = o;
    };

    f16x8 af[4], bfA[4], bfB[4];
    auto RDA = [&](const unsigned short* Ab, int mh, int kk) {
        #pragma unroll
        for (int m = 0; m < 4; ++m) {
            int arow = wr * 128 + (mh * 4 + m) * 16 + lrow;
            int idx = arow * BK + ((kk * 32 + lko) ^ swr);
            af[m] = __builtin_bit_cast(f16x8, *reinterpret_cast<const uint4*>(&Ab[idx]));
        }
    };
    auto DEQB = [&](const uint32_t* Bpb, f16x8* b, int kk) {
        const int dcol = kk * 4 + (lane >> 4);
        const uint32_t MK = 0x000F000Fu, MG = 0x64006400u;
        #pragma unroll
        for (int n = 0; n < 4; ++n) {
            int brow = wc * 64 + n * 16 + lrow;
            uint32_t u = Bpb[brow * 8 + dcol];
            uint32_t p0 = (u & MK) | MG;
            uint32_t p1 = ((u >> 4) & MK) | MG;
            uint32_t p2 = ((u >> 8) & MK) | MG;
            uint32_t p3 = ((u >> 12) & MK) | MG;
            u32x4 o;
            o.x = __builtin_bit_cast(uint32_t, (__builtin_bit_cast(f16x2, p0) - zz[n]) * ss[n]);
            o.y = __builtin_bit_cast(uint32_t, (__builtin_bit_cast(f16x2, p1) - zz[n]) * ss[n]);
            o.z = __builtin_bit_cast(uint32_t, (__builtin_bit_cast(f16x2, p2) - zz[n]) * ss[n]);
            o.w = __builtin_bit_cast(uint32_t, (__builtin_bit_cast(f16x2, p3) - zz[n]) * ss[n]);
            b[n] = __builtin_bit_cast(f16x8, o);
        }
    };
    auto MFMAQ = [&](f16x8* bf, int mh) {
        #pragma unroll
        for (int m_ = 0; m_ < 4; ++m_)
            #pragma unroll
            for (int n_ = 0; n_ < 4; ++n_)
                acc[mh * 4 + m_][n_] = __builtin_amdgcn_mfma_f32_16x16x32_f16(
                    af[m_], bf[n_], acc[mh * 4 + m_][n_], 0, 0, 0);
    };

    PFG(0);
    GLDSB(0, Bp);
    LOADA(0);
    asm volatile("s_waitcnt vmcnt(0)" ::: "memory");
    #pragma unroll
    for (int c = 0; c < 4; ++c) WA(As, c);
    SETG(0);
    __syncthreads();

    for (int t = 0; t < NT; ++t) {
        const int grp = t >> 1;
        if (t && !(t & 1)) SETG(grp);
        if ((t & 1) && grp + 1 < ngrp) PFG(grp + 1);

        const int buf = t & 1;
        const unsigned short* Ab = As + buf * ASZ;
        const uint32_t* Bpb = Bp + buf * BPSZ;
        if (t + 1 < NT) {
            GLDSB((t + 1) * BK, Bp + (buf ^ 1) * BPSZ);
            LOADA((t + 1) * BK);
        }

        DEQB(Bpb, bfA, 0);
        RDA(Ab, 0, 0);
        MFMAQ(bfA, 0);
        RDA(Ab, 1, 0);
        MFMAQ(bfA, 1);
        DEQB(Bpb, bfB, 1);
        RDA(Ab, 0, 1);
        MFMAQ(bfB, 0);
        RDA(Ab, 1, 1);
        MFMAQ(bfB, 1);

        if (t + 1 < NT) { WA(As + (buf ^ 1) * ASZ, 0); WA(As + (buf ^ 1) * ASZ, 1);
                          WA(As + (buf ^ 1) * ASZ, 2); WA(As + (buf ^ 1) * ASZ, 3); }
        __syncthreads();
    }

    const int r4 = (lane >> 4) << 2;
    #pragma unroll
    for (int n = 0; n < 4; ++n) {
        int col = n0 + wc * 64 + n * 16 + lrow;
        float bv = bias[col];
        #pragma unroll
        for (int m = 0; m < 8; ++m) {
            size_t rbase = (size_t)(m0 + wr * 128 + m * 16 + r4) * N + col;
            #pragma unroll
            for (int e = 0; e < 4; ++e)
                __builtin_nontemporal_store(acc[m][n][e] + bv, &out[rbase + (size_t)e * N]);
        }
    }
}

extern "C" void kernel_launch(void* const* d_in, const int* in_sizes, int n_in,
                              void* d_out, int out_size, void* d_ws, size_t ws_size,
                              hipStream_t stream) {
    const float* x   = (const float*)d_in[0];
    const int*   qwp = (const int*)d_in[1];
    const int*   qzp = (const int*)d_in[2];
    const float* scp = (const float*)d_in[3];
    const float* bp  = (const float*)d_in[4];
    float* outp = (float*)d_out;

    const int N = in_sizes[4];                 // 4096 (O)
    const int K = (in_sizes[1] / N) * 8;       // 4096 (I)
    const int M = in_sizes[0] / K;             // 8192 (B)

    dim3 block(512);
    const size_t needX = (size_t)M * K * 2;
    const size_t needW = (size_t)N * K * 2;

    if (ws_size >= needX + needW) {
        unsigned short* xh  = (unsigned short*)d_ws;
        unsigned short* whf = xh + (size_t)M * K;
        int ncx = M * (K / 8), ncw = N * (K / 8);
        convert_x2_kernel<<<dim3((ncx + 255) / 256), dim3(256), 0, stream>>>(x, xh, M, K);
        convert_w3_kernel<<<dim3((ncw + 255) / 256), dim3(256), 0, stream>>>(qwp, qzp, scp, whf, N, K);
        dim3 grid2((M / 256) * (N / 128));     // 1024
        const int ldsbytes = 3 * 256 * 32 * 2; // 48 KB -> 2 blocks/CU
        (void)hipFuncSetAttribute(
            reinterpret_cast<const void*>(&awq_gemm2_kernel),
            hipFuncAttributeMaxDynamicSharedMemorySize, ldsbytes);
        awq_gemm2_kernel<<<grid2, block, ldsbytes, stream>>>(xh, whf, bp, outp, M, N, K);
    } else {
        dim3 grid((M / BM) * (N / BN));
        const int ldsbytes = 2 * BM * BK * 2 + 2 * BN * (BK / 8) * 4;
        (void)hipFuncSetAttribute(
            reinterpret_cast<const void*>(&awq_gemm0_kernel),
            hipFuncAttributeMaxDynamicSharedMemorySize, ldsbytes);
        awq_gemm0_kernel<<<grid, block, ldsbytes, stream>>>(
            x, qwp, qzp, scp, bp, outp, M, N, K);
    }
}